// Round 1
// baseline (369.554 us; speedup 1.0000x reference)
//
#include <hip/hip_runtime.h>

// ---------------- problem constants ----------------
#define NB 4          // batch
#define NC 256        // channels
#define NROW 256
#define NCOL 256
#define PA 64         // patch side
#define NIC 64        // inner channels (attention)
#define NC16 16       // f_test conv channels
// F critical value for F(1, 69630) at alpha=0.05  (pval<0.05 <=> F > FCRIT)
#define FCRIT 3.8415923532

// ---------------- workspace layout (bytes) ----------------
#define OFF_FULL   0u          // double[4][16][2]   (sum,sumsq) of y2 over full image
#define OFF_PATCH  1024u       // double[4][4][16][2] per-layer patch stats (slot l)
#define OFF_S      8192u       // float[4][4][64][64] logits per layer,b
#define OFF_WTS    270336u     // float[4][64][64]    softmax weights (reused per layer)
#define OFF_W3     335872u     // float[192][256]     concat(Wq,Wk,Wv)
#define OFF_B3     532480u     // float[192]
#define OFF_WFT    533248u     // float[256][16]      Wf transposed
#define OFF_Y3     1048576u    // float[4][192][4096] Q(0..63) K(64..127) V(128..191)
#define OFF_A      13631488u   // float[4][64][4096]  att = wts @ V
#define STATS_ZERO_BYTES 270336u

// ---------------- helpers ----------------
static __device__ __forceinline__ double wred(double v) {
#pragma unroll
  for (int off = 32; off > 0; off >>= 1) v += __shfl_down(v, off, 64);
  return v;
}

// Latched stop predicate through layer `upto` (inclusive). Uniform result.
// Lane k (= tid&63) handles (b,o) pair k; ballot+popcount gives counts.
static __device__ __forceinline__ bool is_stopped(const double* __restrict__ fullS,
                                                  const double* __restrict__ patchS,
                                                  int upto) {
  const int k = threadIdx.x & 63;
  const double fs = fullS[2 * k], fq = fullS[2 * k + 1];
  const double m2 = fs * (1.0 / 65536.0);
  const double v2 = fq * (1.0 / 65536.0) - m2 * m2;
  bool stopped = false;
  for (int l = 0; l <= upto; ++l) {
    const double* ps = patchS + (size_t)l * 128;
    const double s1 = ps[2 * k], s2 = ps[2 * k + 1];
    const double m1 = s1 * (1.0 / 4096.0);
    const double v1 = s2 * (1.0 / 4096.0) - m1 * m1;
    const double gm = (4096.0 * m1 + 65536.0 * m2) * (1.0 / 69632.0);
    const double d1 = m1 - gm, d2 = m2 - gm;
    const double ssb = 4096.0 * d1 * d1 + 65536.0 * d2 * d2;
    const double ssw = 4096.0 * v1 + 65536.0 * v2;
    const double F = ssb * (69630.0 / ssw);
    const unsigned long long bal = __ballot(F > FCRIT);
    const int cnt = __popcll(bal);
    stopped = stopped || (2 * cnt >= 64);
  }
  return stopped;
}

static __device__ __forceinline__ void fma16(float acc[4][4], float4 w, float4 v) {
  const float wa[4] = {w.x, w.y, w.z, w.w};
  const float va[4] = {v.x, v.y, v.z, v.w};
#pragma unroll
  for (int a = 0; a < 4; ++a)
#pragma unroll
    for (int c = 0; c < 4; ++c) acc[a][c] += wa[a] * va[c];
}

// patch pixel address in out: (b, c, 192+y, 192+x)
static __device__ __forceinline__ size_t pidx(int b, int c, int y, int x) {
  return (((size_t)b * NC + c) * NROW + 192 + y) * NCOL + 192 + x;
}

// ---------------- setup: pack weights into ws ----------------
__global__ void k_setup(const float* __restrict__ Wq, const float* __restrict__ Wk,
                        const float* __restrict__ Wv, const float* __restrict__ bq,
                        const float* __restrict__ bk, const float* __restrict__ bv,
                        const float* __restrict__ Wf, float* __restrict__ W3,
                        float* __restrict__ b3, float* __restrict__ WfT) {
  for (int i = blockIdx.x * 256 + threadIdx.x; i < 53440; i += gridDim.x * 256) {
    if (i < 49152) {
      int r = i >> 8, c = i & 255;
      float v;
      if (r < 64) v = Wq[r * 256 + c];
      else if (r < 128) v = Wk[(r - 64) * 256 + c];
      else v = Wv[(r - 128) * 256 + c];
      W3[i] = v;
    } else if (i < 49344) {
      int r = i - 49152;
      b3[r] = (r < 64) ? bq[r] : (r < 128) ? bk[r - 64] : bv[r - 128];
    } else {
      int k = i - 49344;       // c*16+o
      int c = k >> 4, o = k & 15;
      WfT[k] = Wf[o * 256 + c];
    }
  }
}

// ---------------- main streaming pass: copy x->out + full/patch y2 stats ----------------
// grid = 4*256 (b,row) blocks, 64 threads; each thread: float4 of one row.
__global__ __launch_bounds__(64) void k_main(const float* __restrict__ x,
                                             const float* __restrict__ Wf,
                                             const float* __restrict__ bf,
                                             float* __restrict__ out,
                                             double* __restrict__ fullS,
                                             double* __restrict__ patchS0) {
  __shared__ __align__(16) float WfT[256 * 16];
  const int t = threadIdx.x;
  const int bb = blockIdx.x >> 8;
  const int row = blockIdx.x & 255;
  for (int r = 0; r < 64; ++r) {
    int idx = r * 64 + t;          // 4096 = 16*256 (o,c)
    int o = idx >> 8, c = idx & 255;
    WfT[c * 16 + o] = Wf[idx];
  }
  __syncthreads();

  float y[16][4];
#pragma unroll
  for (int o = 0; o < 16; ++o) y[o][0] = y[o][1] = y[o][2] = y[o][3] = 0.f;

  const size_t base0 = (size_t)bb * 16777216 + (size_t)row * 256 + t * 4;
#pragma unroll 4
  for (int c = 0; c < 256; ++c) {
    const float4 v = *reinterpret_cast<const float4*>(x + base0 + (size_t)c * 65536);
    *reinterpret_cast<float4*>(out + base0 + (size_t)c * 65536) = v;
    const float4* wf = reinterpret_cast<const float4*>(&WfT[c * 16]);
    const float4 w0 = wf[0], w1 = wf[1], w2 = wf[2], w3 = wf[3];
    const float wv[16] = {w0.x, w0.y, w0.z, w0.w, w1.x, w1.y, w1.z, w1.w,
                          w2.x, w2.y, w2.z, w2.w, w3.x, w3.y, w3.z, w3.w};
#pragma unroll
    for (int o = 0; o < 16; ++o) {
      y[o][0] += wv[o] * v.x;
      y[o][1] += wv[o] * v.y;
      y[o][2] += wv[o] * v.z;
      y[o][3] += wv[o] * v.w;
    }
  }

  const bool rowInPatch = (row >= 192);
  const bool lanePatch = (t >= 48);
#pragma unroll 1
  for (int o = 0; o < 16; ++o) {
    const float b = bf[o];
    double s1 = 0.0, s2 = 0.0;
#pragma unroll
    for (int j = 0; j < 4; ++j) {
      const double yv = (double)(y[o][j] + b);
      s1 += yv;
      s2 += yv * yv;
    }
    const double r1 = wred(s1), r2 = wred(s2);
    if (t == 0) {
      unsafeAtomicAdd(&fullS[(bb * 16 + o) * 2], r1);
      unsafeAtomicAdd(&fullS[(bb * 16 + o) * 2 + 1], r2);
    }
    if (rowInPatch) {
      double p1 = lanePatch ? s1 : 0.0;
      double p2 = lanePatch ? s2 : 0.0;
      p1 = wred(p1);
      p2 = wred(p2);
      if (t == 0) {
        unsafeAtomicAdd(&patchS0[(bb * 16 + o) * 2], p1);
        unsafeAtomicAdd(&patchS0[(bb * 16 + o) * 2 + 1], p2);
      }
    }
  }
}

// ---------------- QKV GEMM: Y3(b,192,4096) = W3 @ patch + b3 ----------------
// grid = 4*3*64, 256 threads, 64x64 tile, 4x4 per thread, K=256.
__global__ __launch_bounds__(256) void k_qkv(const float* __restrict__ out,
                                             const float* __restrict__ W3,
                                             const float* __restrict__ b3,
                                             float* __restrict__ Y3,
                                             const double* __restrict__ fullS,
                                             const double* __restrict__ patchS, int layer) {
  if (is_stopped(fullS, patchS, layer)) return;
  __shared__ __align__(16) float W3T[64][68];
  __shared__ __align__(16) float X2[64 * 64];
  const int t = threadIdx.x;
  const int blk = blockIdx.x;
  const int qt = blk & 63;
  const int mt = (blk >> 6) % 3;
  const int bb = blk / 192;
  const int tq = t & 15, to = t >> 4;
  const int m0 = mt * 64;
  float acc[4][4] = {};
  for (int kc = 0; kc < 4; ++kc) {
    const int k0 = kc * 64;
    __syncthreads();
    for (int r = 0; r < 16; ++r) {
      int idx = r * 256 + t;
      int ml = idx >> 6, kl = idx & 63;
      W3T[kl][ml] = W3[(m0 + ml) * 256 + k0 + kl];
    }
    for (int r = 0; r < 16; ++r) {
      int idx = r * 256 + t;
      int kl = idx >> 6, ql = idx & 63;
      X2[kl * 64 + ql] = out[pidx(bb, k0 + kl, qt, ql)];
    }
    __syncthreads();
#pragma unroll 8
    for (int kk = 0; kk < 64; ++kk) {
      const float4 wv = *reinterpret_cast<const float4*>(&W3T[kk][to * 4]);
      const float4 xv = *reinterpret_cast<const float4*>(&X2[kk * 64 + tq * 4]);
      fma16(acc, wv, xv);
    }
  }
#pragma unroll
  for (int a = 0; a < 4; ++a) {
    const int m = m0 + to * 4 + a;
    const float bias = b3[m];
    float4 res;
    res.x = acc[a][0] + bias;
    res.y = acc[a][1] + bias;
    res.z = acc[a][2] + bias;
    res.w = acc[a][3] + bias;
    *reinterpret_cast<float4*>(&Y3[((size_t)bb * 192 + m) * 4096 + qt * 64 + tq * 4]) = res;
  }
}

// ---------------- S partial: S[b,i,j] += Q[i,m]*Kflat[m*64+j] over m-chunk ----------------
// grid = 4*64 (b, m-chunk of 64), 256 threads, atomic accumulate into S.
__global__ __launch_bounds__(256) void k_s(const float* __restrict__ Y3,
                                           float* __restrict__ Sbase,
                                           const double* __restrict__ fullS,
                                           const double* __restrict__ patchS, int layer) {
  if (is_stopped(fullS, patchS, layer)) return;
  __shared__ __align__(16) float QT[64][68];
  __shared__ __align__(16) float K2[64 * 64];
  const int t = threadIdx.x;
  const int mc = blockIdx.x & 63;
  const int bb = blockIdx.x >> 6;
  const int m0 = mc * 64;
  const float* Q = Y3 + (size_t)bb * 192 * 4096;
  const float* Kf = Q + 64 * 4096;
  for (int r = 0; r < 16; ++r) {
    int idx = r * 256 + t;
    int i = idx >> 6, ml = idx & 63;
    QT[ml][i] = Q[(size_t)i * 4096 + m0 + ml];
  }
  for (int r = 0; r < 16; ++r) {
    int idx = r * 256 + t;
    K2[idx] = Kf[(size_t)m0 * 64 + idx];   // contiguous tile: K'[m0..m0+64, 0..64)
  }
  __syncthreads();
  const int tj = t & 15, ti = t >> 4;
  float acc[4][4] = {};
#pragma unroll 8
  for (int mm = 0; mm < 64; ++mm) {
    const float4 qv = *reinterpret_cast<const float4*>(&QT[mm][ti * 4]);
    const float4 kv = *reinterpret_cast<const float4*>(&K2[mm * 64 + tj * 4]);
    fma16(acc, qv, kv);
  }
  float* Sl = Sbase + (size_t)layer * 16384 + bb * 4096;
#pragma unroll
  for (int a = 0; a < 4; ++a)
#pragma unroll
    for (int c = 0; c < 4; ++c)
      unsafeAtomicAdd(&Sl[(ti * 4 + a) * 64 + tj * 4 + c], acc[a][c]);
}

// ---------------- column softmax over i: wts[b,i,j] ----------------
// grid = 1, 256 threads: thread = (b,j) column.
__global__ __launch_bounds__(256) void k_softmax(const float* __restrict__ Sbase,
                                                 float* __restrict__ wts,
                                                 const double* __restrict__ fullS,
                                                 const double* __restrict__ patchS, int layer) {
  if (is_stopped(fullS, patchS, layer)) return;
  const int t = threadIdx.x;
  const int bb = t >> 6, j = t & 63;
  const float* Sl = Sbase + (size_t)layer * 16384 + bb * 4096;
  float v[64];
#pragma unroll
  for (int i = 0; i < 64; ++i) v[i] = Sl[i * 64 + j];
  float mx = v[0];
#pragma unroll
  for (int i = 1; i < 64; ++i) mx = fmaxf(mx, v[i]);
  float sum = 0.f;
#pragma unroll
  for (int i = 0; i < 64; ++i) {
    v[i] = __expf(v[i] - mx);
    sum += v[i];
  }
  const float inv = 1.f / sum;
#pragma unroll
  for (int i = 0; i < 64; ++i) wts[bb * 4096 + i * 64 + j] = v[i] * inv;
}

// ---------------- A = wts @ V : (b,64,4096) ----------------
// grid = 4*64 (b, m-tile of 64), 256 threads, 4x4 per thread, K=64.
__global__ __launch_bounds__(256) void k_attA(const float* __restrict__ wts,
                                              const float* __restrict__ Y3,
                                              float* __restrict__ A,
                                              const double* __restrict__ fullS,
                                              const double* __restrict__ patchS, int layer) {
  if (is_stopped(fullS, patchS, layer)) return;
  __shared__ __align__(16) float WT[64][68];
  __shared__ __align__(16) float V2[64 * 64];
  const int t = threadIdx.x;
  const int mc = blockIdx.x & 63;
  const int bb = blockIdx.x >> 6;
  const int m0 = mc * 64;
  const float* Vp = Y3 + (size_t)bb * 192 * 4096 + 128 * 4096;
  for (int r = 0; r < 16; ++r) {
    int idx = r * 256 + t;
    int i = idx >> 6, j = idx & 63;
    WT[j][i] = wts[bb * 4096 + idx];
  }
  for (int r = 0; r < 16; ++r) {
    int idx = r * 256 + t;
    V2[idx] = Vp[(size_t)(idx >> 6) * 4096 + m0 + (idx & 63)];
  }
  __syncthreads();
  const int tm = t & 15, ti = t >> 4;
  float acc[4][4] = {};
#pragma unroll 8
  for (int jj = 0; jj < 64; ++jj) {
    const float4 wv = *reinterpret_cast<const float4*>(&WT[jj][ti * 4]);
    const float4 vv = *reinterpret_cast<const float4*>(&V2[jj * 64 + tm * 4]);
    fma16(acc, wv, vv);
  }
#pragma unroll
  for (int a = 0; a < 4; ++a) {
    float4 res;
    res.x = acc[a][0]; res.y = acc[a][1]; res.z = acc[a][2]; res.w = acc[a][3];
    *reinterpret_cast<float4*>(&A[(size_t)bb * 262144 + (size_t)(ti * 4 + a) * 4096 + m0 + tm * 4]) = res;
  }
}

// ---------------- P' = Wr @ A + br + P (in-place on out patch region) ----------------
// grid = 4*4*64 (b, o-tile, q-tile), 256 threads, 4x4 per thread, K=64.
__global__ __launch_bounds__(256) void k_wr(const float* __restrict__ A,
                                            const float* __restrict__ Wr,
                                            const float* __restrict__ br,
                                            float* __restrict__ out,
                                            const double* __restrict__ fullS,
                                            const double* __restrict__ patchS, int layer) {
  if (is_stopped(fullS, patchS, layer)) return;
  __shared__ __align__(16) float WrT[64][68];
  __shared__ __align__(16) float A2[64 * 64];
  const int t = threadIdx.x;
  const int blk = blockIdx.x;
  const int qt = blk & 63;
  const int ot = (blk >> 6) & 3;
  const int bb = blk >> 8;
  const int o0 = ot * 64;
  for (int r = 0; r < 16; ++r) {
    int idx = r * 256 + t;
    int ol = idx >> 6, il = idx & 63;
    WrT[il][ol] = Wr[(o0 + ol) * 64 + il];
  }
  for (int r = 0; r < 16; ++r) {
    int idx = r * 256 + t;
    A2[idx] = A[(size_t)bb * 262144 + (size_t)(idx >> 6) * 4096 + qt * 64 + (idx & 63)];
  }
  __syncthreads();
  const int tq = t & 15, to = t >> 4;
  float acc[4][4] = {};
#pragma unroll 8
  for (int ii = 0; ii < 64; ++ii) {
    const float4 wv = *reinterpret_cast<const float4*>(&WrT[ii][to * 4]);
    const float4 av = *reinterpret_cast<const float4*>(&A2[ii * 64 + tq * 4]);
    fma16(acc, wv, av);
  }
#pragma unroll
  for (int a = 0; a < 4; ++a) {
    const int o = o0 + to * 4 + a;
    const float bro = br[o];
    float* p = out + pidx(bb, o, qt, tq * 4);
    float4 pv = *reinterpret_cast<const float4*>(p);
    pv.x += acc[a][0] + bro;
    pv.y += acc[a][1] + bro;
    pv.z += acc[a][2] + bro;
    pv.w += acc[a][3] + bro;
    *reinterpret_cast<float4*>(p) = pv;
  }
}

// ---------------- F-test stats of current patch -> slot layer+1 ----------------
// grid = 4*16 (b, q-chunk of 256 pixels), 256 threads.
__global__ __launch_bounds__(256) void k_ftest(const float* __restrict__ out,
                                               const float* __restrict__ WfTg,
                                               const float* __restrict__ bf,
                                               double* __restrict__ patchS,
                                               const double* __restrict__ fullS, int layer) {
  if (is_stopped(fullS, patchS, layer)) return;
  const int t = threadIdx.x;
  const int qc = blockIdx.x & 15;
  const int bb = blockIdx.x >> 4;
  const int q = qc * 256 + t;
  const int yrow = q >> 6, xx = q & 63;
  float facc[16] = {};
#pragma unroll 2
  for (int c = 0; c < 256; ++c) {
    const float v = out[pidx(bb, c, yrow, xx)];
    const float4* wf = reinterpret_cast<const float4*>(WfTg + c * 16);
    const float4 w0 = wf[0], w1 = wf[1], w2 = wf[2], w3 = wf[3];
    const float wv[16] = {w0.x, w0.y, w0.z, w0.w, w1.x, w1.y, w1.z, w1.w,
                          w2.x, w2.y, w2.z, w2.w, w3.x, w3.y, w3.z, w3.w};
#pragma unroll
    for (int o = 0; o < 16; ++o) facc[o] += wv[o] * v;
  }
  double* slot = patchS + (size_t)(layer + 1) * 128;
#pragma unroll 1
  for (int o = 0; o < 16; ++o) {
    const double yv = (double)(facc[o] + bf[o]);
    const double r1 = wred(yv);
    const double r2 = wred(yv * yv);
    if ((t & 63) == 0) {
      unsafeAtomicAdd(&slot[(bb * 16 + o) * 2], r1);
      unsafeAtomicAdd(&slot[(bb * 16 + o) * 2 + 1], r2);
    }
  }
}

// ---------------- launch ----------------
extern "C" void kernel_launch(void* const* d_in, const int* in_sizes, int n_in,
                              void* d_out, int out_size, void* d_ws, size_t ws_size,
                              hipStream_t stream) {
  const float* x  = (const float*)d_in[0];
  const float* Wq = (const float*)d_in[1];
  const float* bq = (const float*)d_in[2];
  const float* Wk = (const float*)d_in[3];
  const float* bk = (const float*)d_in[4];
  const float* Wv = (const float*)d_in[5];
  const float* bv = (const float*)d_in[6];
  const float* Wr = (const float*)d_in[7];
  const float* br = (const float*)d_in[8];
  const float* Wf = (const float*)d_in[9];
  const float* bf = (const float*)d_in[10];
  float* out = (float*)d_out;
  char* ws = (char*)d_ws;

  double* fullS  = (double*)(ws + OFF_FULL);
  double* patchS = (double*)(ws + OFF_PATCH);
  float* Sb   = (float*)(ws + OFF_S);
  float* wts  = (float*)(ws + OFF_WTS);
  float* W3   = (float*)(ws + OFF_W3);
  float* b3   = (float*)(ws + OFF_B3);
  float* WfT  = (float*)(ws + OFF_WFT);
  float* Y3   = (float*)(ws + OFF_Y3);
  float* A    = (float*)(ws + OFF_A);

  (void)hipMemsetAsync(ws, 0, STATS_ZERO_BYTES, stream);
  k_setup<<<64, 256, 0, stream>>>(Wq, Wk, Wv, bq, bk, bv, Wf, W3, b3, WfT);
  k_main<<<1024, 64, 0, stream>>>(x, Wf, bf, out, fullS, patchS);
  for (int l = 0; l < 4; ++l) {
    k_qkv<<<768, 256, 0, stream>>>(out, W3, b3, Y3, fullS, patchS, l);
    k_s<<<256, 256, 0, stream>>>(Y3, Sb, fullS, patchS, l);
    k_softmax<<<1, 256, 0, stream>>>(Sb, wts, fullS, patchS, l);
    k_attA<<<256, 256, 0, stream>>>(wts, Y3, A, fullS, patchS, l);
    k_wr<<<1024, 256, 0, stream>>>(A, Wr, br, out, fullS, patchS, l);
    if (l < 3) k_ftest<<<64, 256, 0, stream>>>(out, WfT, bf, patchS, fullS, l);
  }
}

// Round 2
// 260.711 us; speedup vs baseline: 1.4175x; 1.4175x over previous
//
#include <hip/hip_runtime.h>

// ---------------- problem constants ----------------
// F critical value for F(1, 69630) at alpha=0.05  (pval<0.05 <=> F > FCRIT)
#define FCRIT 3.8415923532

// ---------------- workspace layout (bytes) ----------------
#define OFF_FULL   0u          // double[4][16][2]   (sum,sumsq) of y2 over full image
#define OFF_PATCH  1024u       // double[4][4][16][2] per-layer patch stats (slot l)
#define OFF_S      8192u       // float[4][4][64][64] logits per layer,b
#define OFF_Y3     1048576u    // float[4][192][4096] Q(0..63) K(64..127) V(128..191)
#define STATS_ZERO_BYTES 270336u

// ---------------- helpers ----------------
static __device__ __forceinline__ double wred(double v) {
#pragma unroll
  for (int off = 32; off > 0; off >>= 1) v += __shfl_down(v, off, 64);
  return v;
}

// Latched stop predicate through layer `upto` (inclusive). Uniform result.
static __device__ __forceinline__ bool is_stopped(const double* __restrict__ fullS,
                                                  const double* __restrict__ patchS,
                                                  int upto) {
  const int k = threadIdx.x & 63;
  const double fs = fullS[2 * k], fq = fullS[2 * k + 1];
  const double m2 = fs * (1.0 / 65536.0);
  const double v2 = fq * (1.0 / 65536.0) - m2 * m2;
  bool stopped = false;
  for (int l = 0; l <= upto; ++l) {
    const double* ps = patchS + (size_t)l * 128;
    const double s1 = ps[2 * k], s2 = ps[2 * k + 1];
    const double m1 = s1 * (1.0 / 4096.0);
    const double v1 = s2 * (1.0 / 4096.0) - m1 * m1;
    const double gm = (4096.0 * m1 + 65536.0 * m2) * (1.0 / 69632.0);
    const double d1 = m1 - gm, d2 = m2 - gm;
    const double ssb = 4096.0 * d1 * d1 + 65536.0 * d2 * d2;
    const double ssw = 4096.0 * v1 + 65536.0 * v2;
    const double F = ssb * (69630.0 / ssw);
    const unsigned long long bal = __ballot(F > FCRIT);
    const int cnt = __popcll(bal);
    stopped = stopped || (2 * cnt >= 64);
  }
  return stopped;
}

static __device__ __forceinline__ void fma16(float acc[4][4], float4 w, float4 v) {
  const float wa[4] = {w.x, w.y, w.z, w.w};
  const float va[4] = {v.x, v.y, v.z, v.w};
#pragma unroll
  for (int a = 0; a < 4; ++a)
#pragma unroll
    for (int c = 0; c < 4; ++c) acc[a][c] += wa[a] * va[c];
}

// patch pixel address in out: (b, c, 192+y, 192+x)
static __device__ __forceinline__ size_t pidx(int b, int c, int y, int x) {
  return (((size_t)b * 256 + c) * 256 + 192 + y) * 256 + 192 + x;
}

// ---------------- fused copy + conv stats pass ----------------
// grid = 512 (b, row-pair), 256 threads; thread = float2 of one row.
// 8 waves/CU, unroll-8 c loop -> 32KB in flight per CU.
__global__ __launch_bounds__(256) void k_main(const float* __restrict__ x,
                                              const float* __restrict__ Wf,
                                              const float* __restrict__ bf,
                                              float* __restrict__ out,
                                              double* __restrict__ fullS,
                                              double* __restrict__ patchS0) {
  __shared__ __align__(16) float WfT2[16 * 257];
  __shared__ __align__(16) float WfT[256 * 16];
  __shared__ double sm[4][16][2];
  __shared__ double sp[4][16][2];
  const int t = threadIdx.x;
  const int bb = blockIdx.x >> 7;
  const int rp = blockIdx.x & 127;

  // two-step conflict-free Wf transpose stage: global coalesced -> [o][c] -> [c][o]
  for (int r = 0; r < 16; ++r) {
    int idx = r * 256 + t;
    WfT2[(idx >> 8) * 257 + (idx & 255)] = Wf[idx];
  }
  __syncthreads();
  for (int r = 0; r < 16; ++r) {
    int idx = r * 256 + t;
    int c = idx >> 4, o = idx & 15;
    WfT[c * 16 + o] = WfT2[o * 257 + c];
  }
  __syncthreads();

  const int r0 = rp * 2 + (t >> 7);
  const int col2 = (t & 127) * 2;
  const size_t base = (size_t)bb * 16777216 + (size_t)r0 * 256 + col2;
  const float* xp = x + base;
  float* op = out + base;
  const bool pStore = (rp >= 96) && ((t & 127) >= 96);  // pixel in patch region

  float y0[16], y1[16];
#pragma unroll
  for (int o = 0; o < 16; ++o) { y0[o] = 0.f; y1[o] = 0.f; }

  for (int cb = 0; cb < 32; ++cb) {
    double v[8];
#pragma unroll
    for (int u = 0; u < 8; ++u)
      v[u] = *reinterpret_cast<const double*>(xp + (size_t)(cb * 8 + u) * 65536);
#pragma unroll
    for (int u = 0; u < 8; ++u) {
      double* dst = reinterpret_cast<double*>(op + (size_t)(cb * 8 + u) * 65536);
      if (pStore) *dst = v[u];                     // patch region: keep cached (re-read soon)
      else __builtin_nontemporal_store(v[u], dst); // bulk copy: don't evict x from L3
      const int c = cb * 8 + u;
      float2 f = *reinterpret_cast<const float2*>(&v[u]);
      const float4* wf = reinterpret_cast<const float4*>(&WfT[c * 16]);
      const float4 w0 = wf[0], w1 = wf[1], w2 = wf[2], w3 = wf[3];
      const float wv[16] = {w0.x, w0.y, w0.z, w0.w, w1.x, w1.y, w1.z, w1.w,
                            w2.x, w2.y, w2.z, w2.w, w3.x, w3.y, w3.z, w3.w};
#pragma unroll
      for (int o = 0; o < 16; ++o) {
        y0[o] += wv[o] * f.x;
        y1[o] += wv[o] * f.y;
      }
    }
  }

  // stats epilogue: per-wave reduce -> LDS -> one atomic per (block,o,stat)
  const int w = t >> 6, lane = t & 63;
  const bool pBlock = (rp >= 96);
  const bool pLane = ((t & 127) >= 96);
#pragma unroll 1
  for (int o = 0; o < 16; ++o) {
    const float bo = bf[o];
    const double a0 = (double)(y0[o] + bo), a1 = (double)(y1[o] + bo);
    double s1 = a0 + a1, s2 = a0 * a0 + a1 * a1;
    const double r1 = wred(s1), r2 = wred(s2);
    if (lane == 0) { sm[w][o][0] = r1; sm[w][o][1] = r2; }
    if (pBlock) {
      double p1 = pLane ? s1 : 0.0, p2 = pLane ? s2 : 0.0;
      p1 = wred(p1); p2 = wred(p2);
      if (lane == 0) { sp[w][o][0] = p1; sp[w][o][1] = p2; }
    }
  }
  __syncthreads();
  if (t < 32) {
    const int o = t >> 1, wh = t & 1;
    double s = sm[0][o][wh] + sm[1][o][wh] + sm[2][o][wh] + sm[3][o][wh];
    unsafeAtomicAdd(&fullS[(bb * 16 + o) * 2 + wh], s);
    if (pBlock) {
      double p = sp[0][o][wh] + sp[1][o][wh] + sp[2][o][wh] + sp[3][o][wh];
      unsafeAtomicAdd(&patchS0[(bb * 16 + o) * 2 + wh], p);
    }
  }
}

// ---------------- QKV GEMM: Y3(b,192,4096) = [Wq;Wk;Wv] @ patch + bias ----------------
__global__ __launch_bounds__(256) void k_qkv(const float* __restrict__ out,
                                             const float* __restrict__ Wq, const float* __restrict__ bq,
                                             const float* __restrict__ Wk, const float* __restrict__ bk,
                                             const float* __restrict__ Wv, const float* __restrict__ bv,
                                             float* __restrict__ Y3,
                                             const double* __restrict__ fullS,
                                             const double* __restrict__ patchS, int layer) {
  if (is_stopped(fullS, patchS, layer)) return;
  __shared__ __align__(16) float W3T[64][68];
  __shared__ __align__(16) float X2[64 * 64];
  const int t = threadIdx.x;
  const int blk = blockIdx.x;
  const int qt = blk & 63;
  const int mt = (blk >> 6) % 3;
  const int bb = blk / 192;
  const float* Wm = (mt == 0) ? Wq : (mt == 1) ? Wk : Wv;
  const float* bm = (mt == 0) ? bq : (mt == 1) ? bk : bv;
  const int tq = t & 15, to = t >> 4;
  float acc[4][4] = {};
  for (int kc = 0; kc < 4; ++kc) {
    const int k0 = kc * 64;
    __syncthreads();
    for (int r = 0; r < 16; ++r) {
      int idx = r * 256 + t;
      int ml = idx >> 6, kl = idx & 63;
      W3T[kl][ml] = Wm[ml * 256 + k0 + kl];
    }
    for (int r = 0; r < 16; ++r) {
      int idx = r * 256 + t;
      int kl = idx >> 6, ql = idx & 63;
      X2[kl * 64 + ql] = out[pidx(bb, k0 + kl, qt, ql)];
    }
    __syncthreads();
#pragma unroll 8
    for (int kk = 0; kk < 64; ++kk) {
      const float4 wv = *reinterpret_cast<const float4*>(&W3T[kk][to * 4]);
      const float4 xv = *reinterpret_cast<const float4*>(&X2[kk * 64 + tq * 4]);
      fma16(acc, wv, xv);
    }
  }
#pragma unroll
  for (int a = 0; a < 4; ++a) {
    const int ml = to * 4 + a;
    const float bias = bm[ml];
    float4 res;
    res.x = acc[a][0] + bias;
    res.y = acc[a][1] + bias;
    res.z = acc[a][2] + bias;
    res.w = acc[a][3] + bias;
    *reinterpret_cast<float4*>(&Y3[((size_t)bb * 192 + mt * 64 + ml) * 4096 + qt * 64 + tq * 4]) = res;
  }
}

// ---------------- S partial: S[b,i,j] += Q[i,m]*Kflat[m*64+j] over m-chunk ----------------
__global__ __launch_bounds__(256) void k_s(const float* __restrict__ Y3,
                                           float* __restrict__ Sbase,
                                           const double* __restrict__ fullS,
                                           const double* __restrict__ patchS, int layer) {
  if (is_stopped(fullS, patchS, layer)) return;
  __shared__ __align__(16) float QT[64][68];
  __shared__ __align__(16) float K2[64 * 64];
  const int t = threadIdx.x;
  const int mc = blockIdx.x & 63;
  const int bb = blockIdx.x >> 6;
  const int m0 = mc * 64;
  const float* Q = Y3 + (size_t)bb * 192 * 4096;
  const float* Kf = Q + 64 * 4096;
  for (int r = 0; r < 16; ++r) {
    int idx = r * 256 + t;
    int i = idx >> 6, ml = idx & 63;
    QT[ml][i] = Q[(size_t)i * 4096 + m0 + ml];
  }
  for (int r = 0; r < 16; ++r) {
    int idx = r * 256 + t;
    K2[idx] = Kf[(size_t)m0 * 64 + idx];
  }
  __syncthreads();
  const int tj = t & 15, ti = t >> 4;
  float acc[4][4] = {};
#pragma unroll 8
  for (int mm = 0; mm < 64; ++mm) {
    const float4 qv = *reinterpret_cast<const float4*>(&QT[mm][ti * 4]);
    const float4 kv = *reinterpret_cast<const float4*>(&K2[mm * 64 + tj * 4]);
    fma16(acc, qv, kv);
  }
  float* Sl = Sbase + (size_t)layer * 16384 + bb * 4096;
#pragma unroll
  for (int a = 0; a < 4; ++a)
#pragma unroll
    for (int c = 0; c < 4; ++c)
      unsafeAtomicAdd(&Sl[(ti * 4 + a) * 64 + tj * 4 + c], acc[a][c]);
}

// ---------------- fused softmax + A = wts@V + out += Wr@A + br ----------------
// grid = 512: (b, o-half, patch row y). A computed in LDS (redundant per o-half).
__global__ __launch_bounds__(256) void k_awr(const float* __restrict__ Y3,
                                             const float* __restrict__ Sbase,
                                             const float* __restrict__ Wr,
                                             const float* __restrict__ br,
                                             float* __restrict__ out,
                                             const double* __restrict__ fullS,
                                             const double* __restrict__ patchS, int layer) {
  if (is_stopped(fullS, patchS, layer)) return;
  __shared__ __align__(16) float Sw[64 * 68];    // wts stored [j][i]
  __shared__ __align__(16) float AV[64 * 68];    // V block, then A block (aliased)
  __shared__ __align__(16) float WrF[128 * 65];  // this block's 128 Wr rows, [o][i]
  const int t = threadIdx.x;
  const int y = blockIdx.x & 63;
  const int oh = (blockIdx.x >> 6) & 1;
  const int bb = blockIdx.x >> 7;

  // stage V block: AV[j][x] = V[j, y*64+x]
  const float* Vp = Y3 + (size_t)bb * 192 * 4096 + (size_t)128 * 4096 + y * 64;
  for (int r = 0; r < 16; ++r) {
    int idx = r * 256 + t;
    int j = idx >> 6, xx = idx & 63;
    AV[j * 68 + xx] = Vp[(size_t)j * 4096 + xx];
  }
  // stage S transposed: Sw[j][i] = S[i,j]
  const float* Sl = Sbase + (size_t)layer * 16384 + bb * 4096;
  for (int r = 0; r < 16; ++r) {
    int idx = r * 256 + t;
    Sw[(idx & 63) * 68 + (idx >> 6)] = Sl[idx];
  }
  // stage this o-half of Wr: WrF[ol][i]
  for (int r = 0; r < 32; ++r) {
    int idx = r * 256 + t;
    int ol = idx >> 6, i = idx & 63;
    WrF[ol * 65 + i] = Wr[(oh * 128 + ol) * 64 + i];
  }
  __syncthreads();

  // softmax over i within column j (= thread t<64); in-place on Sw row
  if (t < 64) {
    float* colp = &Sw[t * 68];
    float mx = -1e30f;
#pragma unroll
    for (int i = 0; i < 64; ++i) mx = fmaxf(mx, colp[i]);
    float sum = 0.f;
#pragma unroll
    for (int i = 0; i < 64; ++i) {
      float e = __expf(colp[i] - mx);
      colp[i] = e;
      sum += e;
    }
    const float inv = 1.f / sum;
#pragma unroll
    for (int i = 0; i < 64; ++i) colp[i] *= inv;
  }
  __syncthreads();

  // stage1: A[i][x] = sum_j wts[i][j] * V[j][x]
  {
    const int ti = t >> 4, tx = t & 15;
    float acc[4][4] = {};
#pragma unroll 8
    for (int j = 0; j < 64; ++j) {
      const float4 wv = *reinterpret_cast<const float4*>(&Sw[j * 68 + ti * 4]);
      const float4 vv = *reinterpret_cast<const float4*>(&AV[j * 68 + tx * 4]);
      fma16(acc, wv, vv);
    }
    __syncthreads();  // all V reads done before overwriting AV with A
#pragma unroll
    for (int a = 0; a < 4; ++a) {
      float4 res;
      res.x = acc[a][0]; res.y = acc[a][1]; res.z = acc[a][2]; res.w = acc[a][3];
      *reinterpret_cast<float4*>(&AV[(ti * 4 + a) * 68 + tx * 4]) = res;
    }
  }
  __syncthreads();

  // stage2: out[o, y, x] += Wr[o,:] @ A[:, x] + br[o]   (o in this half, 4 o x 8 x per thread)
  const int to = t >> 3, tx8 = t & 7;
  float acc[4][8] = {};
#pragma unroll 4
  for (int i = 0; i < 64; ++i) {
    const float4 a0 = *reinterpret_cast<const float4*>(&AV[i * 68 + tx8 * 8]);
    const float4 a1 = *reinterpret_cast<const float4*>(&AV[i * 68 + tx8 * 8 + 4]);
    const float av[8] = {a0.x, a0.y, a0.z, a0.w, a1.x, a1.y, a1.z, a1.w};
#pragma unroll
    for (int a = 0; a < 4; ++a) {
      const float wv = WrF[(to * 4 + a) * 65 + i];
#pragma unroll
      for (int c = 0; c < 8; ++c) acc[a][c] += wv * av[c];
    }
  }
#pragma unroll
  for (int a = 0; a < 4; ++a) {
    const int o = oh * 128 + to * 4 + a;
    const float bro = br[o];
    float* p = out + pidx(bb, o, y, tx8 * 8);
    float4 p0 = *reinterpret_cast<const float4*>(p);
    float4 p1 = *reinterpret_cast<const float4*>(p + 4);
    p0.x += acc[a][0] + bro; p0.y += acc[a][1] + bro;
    p0.z += acc[a][2] + bro; p0.w += acc[a][3] + bro;
    p1.x += acc[a][4] + bro; p1.y += acc[a][5] + bro;
    p1.z += acc[a][6] + bro; p1.w += acc[a][7] + bro;
    *reinterpret_cast<float4*>(p) = p0;
    *reinterpret_cast<float4*>(p + 4) = p1;
  }
}

// ---------------- F-test stats of current patch -> slot layer+1 ----------------
// grid = 128 (b, row-pair), 256 threads = 128 px x 2 channel-halves; LDS combine.
__global__ __launch_bounds__(256) void k_ftest(const float* __restrict__ out,
                                               const float* __restrict__ Wf,
                                               const float* __restrict__ bf,
                                               double* __restrict__ patchS,
                                               const double* __restrict__ fullS, int layer) {
  if (is_stopped(fullS, patchS, layer)) return;
  __shared__ __align__(16) float WfT2[16 * 257];
  __shared__ __align__(16) float WfT[256 * 16];
  __shared__ float part[2 * 128 * 17];
  __shared__ double red[16][16][2];
  const int t = threadIdx.x;
  const int bb = blockIdx.x >> 5;
  const int rg = blockIdx.x & 31;

  for (int r = 0; r < 16; ++r) {
    int idx = r * 256 + t;
    WfT2[(idx >> 8) * 257 + (idx & 255)] = Wf[idx];
  }
  __syncthreads();
  for (int r = 0; r < 16; ++r) {
    int idx = r * 256 + t;
    int c = idx >> 4, o = idx & 15;
    WfT[c * 16 + o] = WfT2[o * 257 + c];
  }
  __syncthreads();

  const int h = t >> 7;          // channel half
  const int px = t & 127;
  const int row = 192 + rg * 2 + (px >> 6);
  const int col = 192 + (px & 63);
  const size_t base = (size_t)bb * 16777216 + (size_t)h * 128 * 65536 + (size_t)row * 256 + col;

  float y[16] = {};
  for (int cb = 0; cb < 16; ++cb) {
    float v[8];
#pragma unroll
    for (int u = 0; u < 8; ++u)
      v[u] = out[base + (size_t)(cb * 8 + u) * 65536];
#pragma unroll
    for (int u = 0; u < 8; ++u) {
      const int c = h * 128 + cb * 8 + u;
      const float4* wf = reinterpret_cast<const float4*>(&WfT[c * 16]);
      const float4 w0 = wf[0], w1 = wf[1], w2 = wf[2], w3 = wf[3];
      const float wv[16] = {w0.x, w0.y, w0.z, w0.w, w1.x, w1.y, w1.z, w1.w,
                            w2.x, w2.y, w2.z, w2.w, w3.x, w3.y, w3.z, w3.w};
#pragma unroll
      for (int o = 0; o < 16; ++o) y[o] += wv[o] * v[u];
    }
  }
#pragma unroll
  for (int o = 0; o < 16; ++o) part[(h * 128 + px) * 17 + o] = y[o];
  __syncthreads();

  const int oo = t & 15, pxg = t >> 4;
  double s1 = 0.0, s2 = 0.0;
  const float bo = bf[oo];
#pragma unroll
  for (int j = 0; j < 8; ++j) {
    const int p = pxg * 8 + j;
    const float yv = part[p * 17 + oo] + part[(128 + p) * 17 + oo] + bo;
    const double v = (double)yv;
    s1 += v;
    s2 += v * v;
  }
  red[oo][pxg][0] = s1;
  red[oo][pxg][1] = s2;
  __syncthreads();
  if (t < 32) {
    const int o = t >> 1, wh = t & 1;
    double s = 0.0;
#pragma unroll
    for (int g = 0; g < 16; ++g) s += red[o][g][wh];
    unsafeAtomicAdd(&patchS[(size_t)(layer + 1) * 128 + (bb * 16 + o) * 2 + wh], s);
  }
}

// ---------------- launch ----------------
extern "C" void kernel_launch(void* const* d_in, const int* in_sizes, int n_in,
                              void* d_out, int out_size, void* d_ws, size_t ws_size,
                              hipStream_t stream) {
  const float* x  = (const float*)d_in[0];
  const float* Wq = (const float*)d_in[1];
  const float* bq = (const float*)d_in[2];
  const float* Wk = (const float*)d_in[3];
  const float* bk = (const float*)d_in[4];
  const float* Wv = (const float*)d_in[5];
  const float* bv = (const float*)d_in[6];
  const float* Wr = (const float*)d_in[7];
  const float* br = (const float*)d_in[8];
  const float* Wf = (const float*)d_in[9];
  const float* bf = (const float*)d_in[10];
  float* out = (float*)d_out;
  char* ws = (char*)d_ws;

  double* fullS  = (double*)(ws + OFF_FULL);
  double* patchS = (double*)(ws + OFF_PATCH);
  float* Sb = (float*)(ws + OFF_S);
  float* Y3 = (float*)(ws + OFF_Y3);

  (void)hipMemsetAsync(ws, 0, STATS_ZERO_BYTES, stream);
  k_main<<<512, 256, 0, stream>>>(x, Wf, bf, out, fullS, patchS);
  for (int l = 0; l < 4; ++l) {
    k_qkv<<<768, 256, 0, stream>>>(out, Wq, bq, Wk, bk, Wv, bv, Y3, fullS, patchS, l);
    k_s<<<256, 256, 0, stream>>>(Y3, Sb, fullS, patchS, l);
    k_awr<<<512, 256, 0, stream>>>(Y3, Sb, Wr, br, out, fullS, patchS, l);
    if (l < 3) k_ftest<<<128, 256, 0, stream>>>(out, Wf, bf, patchS, fullS, l);
  }
}

// Round 3
// 252.393 us; speedup vs baseline: 1.4642x; 1.0330x over previous
//
#include <hip/hip_runtime.h>

// ---------------- problem constants ----------------
// F critical value for F(1, 69630) at alpha=0.05  (pval<0.05 <=> F > FCRIT)
#define FCRIT 3.8415923532

// ---------------- workspace layout (bytes) ----------------
#define OFF_FULL   0u          // double[4][16][2]   (sum,sumsq) of y2 over full image
#define OFF_PATCH  1024u       // double[4][4][16][2] per-layer patch stats (slot l)
#define OFF_S      8192u       // float[4][4][64][64] logits per layer,b
#define OFF_Y3     1048576u    // float[4][192][4096] Q(0..63) K(64..127) V(128..191)
#define OFF_XH     16777216u   // ushort[3][4][4096][256] bf16 splits of patch, [px][ch]
#define OFF_WH     41943040u   // ushort[3][192][256]     bf16 splits of Wq|Wk|Wv
#define STATS_ZERO_BYTES 270336u

typedef __attribute__((ext_vector_type(8))) short short8;
typedef __attribute__((ext_vector_type(8))) unsigned short us8;
typedef __attribute__((ext_vector_type(4))) float f32x4;

// ---------------- helpers ----------------
static __device__ __forceinline__ double wred(double v) {
#pragma unroll
  for (int off = 32; off > 0; off >>= 1) v += __shfl_down(v, off, 64);
  return v;
}

static __device__ __forceinline__ unsigned short f2bf(float f) {
  union { float f; unsigned u; } v; v.f = f;
  unsigned r = v.u + 0x7fffu + ((v.u >> 16) & 1u);   // RNE
  return (unsigned short)(r >> 16);
}
static __device__ __forceinline__ float bf2f(unsigned short h) {
  union { unsigned u; float f; } v; v.u = ((unsigned)h) << 16;
  return v.f;
}

// Latched stop predicate through layer `upto` (inclusive). Uniform result.
static __device__ __forceinline__ bool is_stopped(const double* __restrict__ fullS,
                                                  const double* __restrict__ patchS,
                                                  int upto) {
  const int k = threadIdx.x & 63;
  const double fs = fullS[2 * k], fq = fullS[2 * k + 1];
  const double m2 = fs * (1.0 / 65536.0);
  const double v2 = fq * (1.0 / 65536.0) - m2 * m2;
  bool stopped = false;
  for (int l = 0; l <= upto; ++l) {
    const double* ps = patchS + (size_t)l * 128;
    const double s1 = ps[2 * k], s2 = ps[2 * k + 1];
    const double m1 = s1 * (1.0 / 4096.0);
    const double v1 = s2 * (1.0 / 4096.0) - m1 * m1;
    const double gm = (4096.0 * m1 + 65536.0 * m2) * (1.0 / 69632.0);
    const double d1 = m1 - gm, d2 = m2 - gm;
    const double ssb = 4096.0 * d1 * d1 + 65536.0 * d2 * d2;
    const double ssw = 4096.0 * v1 + 65536.0 * v2;
    const double F = ssb * (69630.0 / ssw);
    const unsigned long long bal = __ballot(F > FCRIT);
    const int cnt = __popcll(bal);
    stopped = stopped || (2 * cnt >= 64);
  }
  return stopped;
}

static __device__ __forceinline__ void fma16(float acc[4][4], float4 w, float4 v) {
  const float wa[4] = {w.x, w.y, w.z, w.w};
  const float va[4] = {v.x, v.y, v.z, v.w};
#pragma unroll
  for (int a = 0; a < 4; ++a)
#pragma unroll
    for (int c = 0; c < 4; ++c) acc[a][c] += wa[a] * va[c];
}

// patch pixel address in out: (b, c, 192+y, 192+x)
static __device__ __forceinline__ size_t pidx(int b, int c, int y, int x) {
  return (((size_t)b * 256 + c) * 256 + 192 + y) * 256 + 192 + x;
}

// ---------------- weight conversion (once): Wq|Wk|Wv -> 3-level bf16 ----------------
__global__ __launch_bounds__(256) void k_wcvt(const float* __restrict__ Wq,
                                              const float* __restrict__ Wk,
                                              const float* __restrict__ Wv,
                                              unsigned short* __restrict__ Whml) {
  const int idx0 = (blockIdx.x * 256 + threadIdx.x) * 4;   // grid 48 -> 49152 elems
#pragma unroll
  for (int u = 0; u < 4; ++u) {
    const int i = idx0 + u;
    const int row = i >> 8, col = i & 255;
    const float v = (row < 64) ? Wq[row * 256 + col]
                  : (row < 128) ? Wk[(row - 64) * 256 + col]
                                : Wv[(row - 128) * 256 + col];
    const unsigned short h = f2bf(v);
    const float r1 = v - bf2f(h);
    const unsigned short m = f2bf(r1);
    const float r2 = r1 - bf2f(m);
    const unsigned short l = f2bf(r2);
    Whml[i] = h;
    Whml[49152 + i] = m;
    Whml[98304 + i] = l;
  }
}

// ---------------- fused copy + conv stats pass ----------------
__global__ __launch_bounds__(256) void k_main(const float* __restrict__ x,
                                              const float* __restrict__ Wf,
                                              const float* __restrict__ bf,
                                              float* __restrict__ out,
                                              double* __restrict__ fullS,
                                              double* __restrict__ patchS0) {
  __shared__ __align__(16) float WfT2[16 * 257];
  __shared__ __align__(16) float WfT[256 * 16];
  __shared__ double sm[4][16][2];
  __shared__ double sp[4][16][2];
  const int t = threadIdx.x;
  const int bb = blockIdx.x >> 7;
  const int rp = blockIdx.x & 127;

  for (int r = 0; r < 16; ++r) {
    int idx = r * 256 + t;
    WfT2[(idx >> 8) * 257 + (idx & 255)] = Wf[idx];
  }
  __syncthreads();
  for (int r = 0; r < 16; ++r) {
    int idx = r * 256 + t;
    int c = idx >> 4, o = idx & 15;
    WfT[c * 16 + o] = WfT2[o * 257 + c];
  }
  __syncthreads();

  const int r0 = rp * 2 + (t >> 7);
  const int col2 = (t & 127) * 2;
  const size_t base = (size_t)bb * 16777216 + (size_t)r0 * 256 + col2;
  const float* xp = x + base;
  float* op = out + base;
  const bool pStore = (rp >= 96) && ((t & 127) >= 96);

  float y0[16], y1[16];
#pragma unroll
  for (int o = 0; o < 16; ++o) { y0[o] = 0.f; y1[o] = 0.f; }

  for (int cb = 0; cb < 32; ++cb) {
    double v[8];
#pragma unroll
    for (int u = 0; u < 8; ++u)
      v[u] = *reinterpret_cast<const double*>(xp + (size_t)(cb * 8 + u) * 65536);
#pragma unroll
    for (int u = 0; u < 8; ++u) {
      double* dst = reinterpret_cast<double*>(op + (size_t)(cb * 8 + u) * 65536);
      if (pStore) *dst = v[u];
      else __builtin_nontemporal_store(v[u], dst);
      const int c = cb * 8 + u;
      float2 f = *reinterpret_cast<const float2*>(&v[u]);
      const float4* wf = reinterpret_cast<const float4*>(&WfT[c * 16]);
      const float4 w0 = wf[0], w1 = wf[1], w2 = wf[2], w3 = wf[3];
      const float wv[16] = {w0.x, w0.y, w0.z, w0.w, w1.x, w1.y, w1.z, w1.w,
                            w2.x, w2.y, w2.z, w2.w, w3.x, w3.y, w3.z, w3.w};
#pragma unroll
      for (int o = 0; o < 16; ++o) {
        y0[o] += wv[o] * f.x;
        y1[o] += wv[o] * f.y;
      }
    }
  }

  const int w = t >> 6, lane = t & 63;
  const bool pBlock = (rp >= 96);
  const bool pLane = ((t & 127) >= 96);
#pragma unroll 1
  for (int o = 0; o < 16; ++o) {
    const float bo = bf[o];
    const double a0 = (double)(y0[o] + bo), a1 = (double)(y1[o] + bo);
    double s1 = a0 + a1, s2 = a0 * a0 + a1 * a1;
    const double r1 = wred(s1), r2 = wred(s2);
    if (lane == 0) { sm[w][o][0] = r1; sm[w][o][1] = r2; }
    if (pBlock) {
      double p1 = pLane ? s1 : 0.0, p2 = pLane ? s2 : 0.0;
      p1 = wred(p1); p2 = wred(p2);
      if (lane == 0) { sp[w][o][0] = p1; sp[w][o][1] = p2; }
    }
  }
  __syncthreads();
  if (t < 32) {
    const int o = t >> 1, wh = t & 1;
    double s = sm[0][o][wh] + sm[1][o][wh] + sm[2][o][wh] + sm[3][o][wh];
    unsafeAtomicAdd(&fullS[(bb * 16 + o) * 2 + wh], s);
    if (pBlock) {
      double p = sp[0][o][wh] + sp[1][o][wh] + sp[2][o][wh] + sp[3][o][wh];
      unsafeAtomicAdd(&patchS0[(bb * 16 + o) * 2 + wh], p);
    }
  }
}

// ---------------- patch -> 3-level bf16 split, transposed to [px][ch] ----------------
// grid = 256 (b, y); LDS transpose for coalesced global stores.
__global__ __launch_bounds__(256) void k_xcvt(const float* __restrict__ out,
                                              unsigned short* __restrict__ Xhml,
                                              const double* __restrict__ fullS,
                                              const double* __restrict__ patchS, int layer) {
  if (is_stopped(fullS, patchS, layer)) return;
  __shared__ float T[256 * 65];
  const int t = threadIdx.x;
  const int bb = blockIdx.x >> 6;
  const int y = blockIdx.x & 63;
  for (int r = 0; r < 64; ++r) {
    int idx = r * 256 + t;
    T[(idx >> 6) * 65 + (idx & 63)] = out[pidx(bb, idx >> 6, y, idx & 63)];
  }
  __syncthreads();
  const int px = t >> 2, c0 = (t & 3) * 64;
  const size_t dstbase = ((size_t)bb * 4096 + y * 64 + px) * 256 + c0;
#pragma unroll 1
  for (int g = 0; g < 8; ++g) {
    us8 hv, mv, lv;
#pragma unroll
    for (int j = 0; j < 8; ++j) {
      const float v = T[(c0 + g * 8 + j) * 65 + px];
      const unsigned short h = f2bf(v);
      const float r1 = v - bf2f(h);
      const unsigned short m = f2bf(r1);
      const float r2 = r1 - bf2f(m);
      const unsigned short l = f2bf(r2);
      hv[j] = (unsigned short)h; mv[j] = m; lv[j] = l;
    }
    *reinterpret_cast<us8*>(Xhml + dstbase + g * 8) = hv;
    *reinterpret_cast<us8*>(Xhml + 4194304u + dstbase + g * 8) = mv;
    *reinterpret_cast<us8*>(Xhml + 8388608u + dstbase + g * 8) = lv;
  }
}

// ---------------- QKV GEMM via 6-term bf16-split MFMA ----------------
// grid = 384: ntile(32) x mt(3) x b(4); 256 thr = 4 waves; block tile 64(m) x 128(n), K=256.
__global__ __launch_bounds__(256) void k_qkv(const unsigned short* __restrict__ Whml,
                                             const float* __restrict__ bq,
                                             const float* __restrict__ bk,
                                             const float* __restrict__ bv,
                                             const unsigned short* __restrict__ Xhml,
                                             float* __restrict__ Y3,
                                             const double* __restrict__ fullS,
                                             const double* __restrict__ patchS, int layer) {
  if (is_stopped(fullS, patchS, layer)) return;
  __shared__ __align__(16) unsigned short Al[3][64][40];
  __shared__ __align__(16) unsigned short Bl[3][128][40];
  const int t = threadIdx.x;
  const int nt = blockIdx.x & 31;
  const int mt = (blockIdx.x >> 5) % 3;
  const int bb = blockIdx.x / 96;
  const int w = t >> 6, lane = t & 63;
  const int lo16 = lane & 15, hi4 = lane >> 4;

  f32x4 acc[4][2];
#pragma unroll
  for (int mf = 0; mf < 4; ++mf)
#pragma unroll
    for (int nf = 0; nf < 2; ++nf) acc[mf][nf] = (f32x4)0.f;

  const unsigned short* Wbase = Whml + mt * 64 * 256;
  const unsigned short* Xbase = Xhml + ((size_t)bb * 4096 + nt * 128) * 256;
  const int am = t >> 2, ak = (t & 3) * 8;       // A staging coords
  const int bpx = t >> 1, bkh = (t & 1) * 16;    // B staging coords

  for (int kc = 0; kc < 8; ++kc) {
    const int k0 = kc * 32;
    __syncthreads();
#pragma unroll
    for (int lev = 0; lev < 3; ++lev) {
      const us8 va = *reinterpret_cast<const us8*>(Wbase + lev * 49152 + am * 256 + k0 + ak);
      *reinterpret_cast<us8*>(&Al[lev][am][ak]) = va;
      const unsigned short* s = Xbase + (size_t)lev * 4194304 + (size_t)bpx * 256 + k0 + bkh;
      const us8 v0 = *reinterpret_cast<const us8*>(s);
      const us8 v1 = *reinterpret_cast<const us8*>(s + 8);
      *reinterpret_cast<us8*>(&Bl[lev][bpx][bkh]) = v0;
      *reinterpret_cast<us8*>(&Bl[lev][bpx][bkh + 8]) = v1;
    }
    __syncthreads();

    short8 af[3][4], bfr[3][2];
    const int koff = hi4 * 8;
#pragma unroll
    for (int lev = 0; lev < 3; ++lev) {
#pragma unroll
      for (int mf = 0; mf < 4; ++mf)
        af[lev][mf] = *reinterpret_cast<const short8*>(&Al[lev][mf * 16 + lo16][koff]);
#pragma unroll
      for (int nf = 0; nf < 2; ++nf)
        bfr[lev][nf] = *reinterpret_cast<const short8*>(&Bl[lev][w * 32 + nf * 16 + lo16][koff]);
    }
#pragma unroll
    for (int mf = 0; mf < 4; ++mf)
#pragma unroll
      for (int nf = 0; nf < 2; ++nf) {
        f32x4 c = acc[mf][nf];
        c = __builtin_amdgcn_mfma_f32_16x16x32_bf16(af[0][mf], bfr[0][nf], c, 0, 0, 0);
        c = __builtin_amdgcn_mfma_f32_16x16x32_bf16(af[0][mf], bfr[1][nf], c, 0, 0, 0);
        c = __builtin_amdgcn_mfma_f32_16x16x32_bf16(af[1][mf], bfr[0][nf], c, 0, 0, 0);
        c = __builtin_amdgcn_mfma_f32_16x16x32_bf16(af[0][mf], bfr[2][nf], c, 0, 0, 0);
        c = __builtin_amdgcn_mfma_f32_16x16x32_bf16(af[2][mf], bfr[0][nf], c, 0, 0, 0);
        c = __builtin_amdgcn_mfma_f32_16x16x32_bf16(af[1][mf], bfr[1][nf], c, 0, 0, 0);
        acc[mf][nf] = c;
      }
  }

  const float* bias = (mt == 0) ? bq : (mt == 1) ? bk : bv;
#pragma unroll
  for (int mf = 0; mf < 4; ++mf)
#pragma unroll
    for (int nf = 0; nf < 2; ++nf)
#pragma unroll
      for (int r = 0; r < 4; ++r) {
        const int mrow = mf * 16 + hi4 * 4 + r;
        const int col = nt * 128 + w * 32 + nf * 16 + lo16;
        Y3[((size_t)bb * 192 + mt * 64 + mrow) * 4096 + col] = acc[mf][nf][r] + bias[mrow];
      }
}

// ---------------- S partial: S[b,i,j] += Q[i,m]*Kflat[m*64+j] over m-chunk ----------------
__global__ __launch_bounds__(256) void k_s(const float* __restrict__ Y3,
                                           float* __restrict__ Sbase,
                                           const double* __restrict__ fullS,
                                           const double* __restrict__ patchS, int layer) {
  if (is_stopped(fullS, patchS, layer)) return;
  __shared__ __align__(16) float QT[64][68];
  __shared__ __align__(16) float K2[64 * 64];
  const int t = threadIdx.x;
  const int mc = blockIdx.x & 63;
  const int bb = blockIdx.x >> 6;
  const int m0 = mc * 64;
  const float* Q = Y3 + (size_t)bb * 192 * 4096;
  const float* Kf = Q + 64 * 4096;
  for (int r = 0; r < 16; ++r) {
    int idx = r * 256 + t;
    int i = idx >> 6, ml = idx & 63;
    QT[ml][i] = Q[(size_t)i * 4096 + m0 + ml];
  }
  for (int r = 0; r < 16; ++r) {
    int idx = r * 256 + t;
    K2[idx] = Kf[(size_t)m0 * 64 + idx];
  }
  __syncthreads();
  const int tj = t & 15, ti = t >> 4;
  float acc[4][4] = {};
#pragma unroll 8
  for (int mm = 0; mm < 64; ++mm) {
    const float4 qv = *reinterpret_cast<const float4*>(&QT[mm][ti * 4]);
    const float4 kv = *reinterpret_cast<const float4*>(&K2[mm * 64 + tj * 4]);
    fma16(acc, qv, kv);
  }
  float* Sl = Sbase + (size_t)layer * 16384 + bb * 4096;
#pragma unroll
  for (int a = 0; a < 4; ++a)
#pragma unroll
    for (int c = 0; c < 4; ++c)
      unsafeAtomicAdd(&Sl[(ti * 4 + a) * 64 + tj * 4 + c], acc[a][c]);
}

// ---------------- fused softmax + A = wts@V + out += Wr@A + br ----------------
__global__ __launch_bounds__(256) void k_awr(const float* __restrict__ Y3,
                                             const float* __restrict__ Sbase,
                                             const float* __restrict__ Wr,
                                             const float* __restrict__ br,
                                             float* __restrict__ out,
                                             const double* __restrict__ fullS,
                                             const double* __restrict__ patchS, int layer) {
  if (is_stopped(fullS, patchS, layer)) return;
  __shared__ __align__(16) float Sw[64 * 68];
  __shared__ __align__(16) float AV[64 * 68];
  __shared__ __align__(16) float WrF[128 * 65];
  const int t = threadIdx.x;
  const int y = blockIdx.x & 63;
  const int oh = (blockIdx.x >> 6) & 1;
  const int bb = blockIdx.x >> 7;

  const float* Vp = Y3 + (size_t)bb * 192 * 4096 + (size_t)128 * 4096 + y * 64;
  for (int r = 0; r < 16; ++r) {
    int idx = r * 256 + t;
    int j = idx >> 6, xx = idx & 63;
    AV[j * 68 + xx] = Vp[(size_t)j * 4096 + xx];
  }
  const float* Sl = Sbase + (size_t)layer * 16384 + bb * 4096;
  for (int r = 0; r < 16; ++r) {
    int idx = r * 256 + t;
    Sw[(idx & 63) * 68 + (idx >> 6)] = Sl[idx];
  }
  for (int r = 0; r < 32; ++r) {
    int idx = r * 256 + t;
    int ol = idx >> 6, i = idx & 63;
    WrF[ol * 65 + i] = Wr[(oh * 128 + ol) * 64 + i];
  }
  __syncthreads();

  if (t < 64) {
    float* colp = &Sw[t * 68];
    float mx = -1e30f;
#pragma unroll
    for (int i = 0; i < 64; ++i) mx = fmaxf(mx, colp[i]);
    float sum = 0.f;
#pragma unroll
    for (int i = 0; i < 64; ++i) {
      float e = __expf(colp[i] - mx);
      colp[i] = e;
      sum += e;
    }
    const float inv = 1.f / sum;
#pragma unroll
    for (int i = 0; i < 64; ++i) colp[i] *= inv;
  }
  __syncthreads();

  {
    const int ti = t >> 4, tx = t & 15;
    float acc[4][4] = {};
#pragma unroll 8
    for (int j = 0; j < 64; ++j) {
      const float4 wv = *reinterpret_cast<const float4*>(&Sw[j * 68 + ti * 4]);
      const float4 vv = *reinterpret_cast<const float4*>(&AV[j * 68 + tx * 4]);
      fma16(acc, wv, vv);
    }
    __syncthreads();
#pragma unroll
    for (int a = 0; a < 4; ++a) {
      float4 res;
      res.x = acc[a][0]; res.y = acc[a][1]; res.z = acc[a][2]; res.w = acc[a][3];
      *reinterpret_cast<float4*>(&AV[(ti * 4 + a) * 68 + tx * 4]) = res;
    }
  }
  __syncthreads();

  const int to = t >> 3, tx8 = t & 7;
  float acc[4][8] = {};
#pragma unroll 4
  for (int i = 0; i < 64; ++i) {
    const float4 a0 = *reinterpret_cast<const float4*>(&AV[i * 68 + tx8 * 8]);
    const float4 a1 = *reinterpret_cast<const float4*>(&AV[i * 68 + tx8 * 8 + 4]);
    const float av[8] = {a0.x, a0.y, a0.z, a0.w, a1.x, a1.y, a1.z, a1.w};
#pragma unroll
    for (int a = 0; a < 4; ++a) {
      const float wv = WrF[(to * 4 + a) * 65 + i];
#pragma unroll
      for (int c = 0; c < 8; ++c) acc[a][c] += wv * av[c];
    }
  }
#pragma unroll
  for (int a = 0; a < 4; ++a) {
    const int o = oh * 128 + to * 4 + a;
    const float bro = br[o];
    float* p = out + pidx(bb, o, y, tx8 * 8);
    float4 p0 = *reinterpret_cast<const float4*>(p);
    float4 p1 = *reinterpret_cast<const float4*>(p + 4);
    p0.x += acc[a][0] + bro; p0.y += acc[a][1] + bro;
    p0.z += acc[a][2] + bro; p0.w += acc[a][3] + bro;
    p1.x += acc[a][4] + bro; p1.y += acc[a][5] + bro;
    p1.z += acc[a][6] + bro; p1.w += acc[a][7] + bro;
    *reinterpret_cast<float4*>(p) = p0;
    *reinterpret_cast<float4*>(p + 4) = p1;
  }
}

// ---------------- F-test stats of current patch -> slot layer+1 ----------------
__global__ __launch_bounds__(256) void k_ftest(const float* __restrict__ out,
                                               const float* __restrict__ Wf,
                                               const float* __restrict__ bf,
                                               double* __restrict__ patchS,
                                               const double* __restrict__ fullS, int layer) {
  if (is_stopped(fullS, patchS, layer)) return;
  __shared__ __align__(16) float WfT2[16 * 257];
  __shared__ __align__(16) float WfT[256 * 16];
  __shared__ float part[2 * 128 * 17];
  __shared__ double red[16][16][2];
  const int t = threadIdx.x;
  const int bb = blockIdx.x >> 5;
  const int rg = blockIdx.x & 31;

  for (int r = 0; r < 16; ++r) {
    int idx = r * 256 + t;
    WfT2[(idx >> 8) * 257 + (idx & 255)] = Wf[idx];
  }
  __syncthreads();
  for (int r = 0; r < 16; ++r) {
    int idx = r * 256 + t;
    int c = idx >> 4, o = idx & 15;
    WfT[c * 16 + o] = WfT2[o * 257 + c];
  }
  __syncthreads();

  const int h = t >> 7;
  const int px = t & 127;
  const int row = 192 + rg * 2 + (px >> 6);
  const int col = 192 + (px & 63);
  const size_t base = (size_t)bb * 16777216 + (size_t)h * 128 * 65536 + (size_t)row * 256 + col;

  float y[16] = {};
  for (int cb = 0; cb < 16; ++cb) {
    float v[8];
#pragma unroll
    for (int u = 0; u < 8; ++u)
      v[u] = out[base + (size_t)(cb * 8 + u) * 65536];
#pragma unroll
    for (int u = 0; u < 8; ++u) {
      const int c = h * 128 + cb * 8 + u;
      const float4* wf = reinterpret_cast<const float4*>(&WfT[c * 16]);
      const float4 w0 = wf[0], w1 = wf[1], w2 = wf[2], w3 = wf[3];
      const float wv[16] = {w0.x, w0.y, w0.z, w0.w, w1.x, w1.y, w1.z, w1.w,
                            w2.x, w2.y, w2.z, w2.w, w3.x, w3.y, w3.z, w3.w};
#pragma unroll
      for (int o = 0; o < 16; ++o) y[o] += wv[o] * v[u];
    }
  }
#pragma unroll
  for (int o = 0; o < 16; ++o) part[(h * 128 + px) * 17 + o] = y[o];
  __syncthreads();

  const int oo = t & 15, pxg = t >> 4;
  double s1 = 0.0, s2 = 0.0;
  const float bo = bf[oo];
#pragma unroll
  for (int j = 0; j < 8; ++j) {
    const int p = pxg * 8 + j;
    const float yv = part[p * 17 + oo] + part[(128 + p) * 17 + oo] + bo;
    const double v = (double)yv;
    s1 += v;
    s2 += v * v;
  }
  red[oo][pxg][0] = s1;
  red[oo][pxg][1] = s2;
  __syncthreads();
  if (t < 32) {
    const int o = t >> 1, wh = t & 1;
    double s = 0.0;
#pragma unroll
    for (int g = 0; g < 16; ++g) s += red[o][g][wh];
    unsafeAtomicAdd(&patchS[(size_t)(layer + 1) * 128 + (bb * 16 + o) * 2 + wh], s);
  }
}

// ---------------- launch ----------------
extern "C" void kernel_launch(void* const* d_in, const int* in_sizes, int n_in,
                              void* d_out, int out_size, void* d_ws, size_t ws_size,
                              hipStream_t stream) {
  const float* x  = (const float*)d_in[0];
  const float* Wq = (const float*)d_in[1];
  const float* bq = (const float*)d_in[2];
  const float* Wk = (const float*)d_in[3];
  const float* bk = (const float*)d_in[4];
  const float* Wv = (const float*)d_in[5];
  const float* bv = (const float*)d_in[6];
  const float* Wr = (const float*)d_in[7];
  const float* br = (const float*)d_in[8];
  const float* Wf = (const float*)d_in[9];
  const float* bf = (const float*)d_in[10];
  float* out = (float*)d_out;
  char* ws = (char*)d_ws;

  double* fullS  = (double*)(ws + OFF_FULL);
  double* patchS = (double*)(ws + OFF_PATCH);
  float* Sb = (float*)(ws + OFF_S);
  float* Y3 = (float*)(ws + OFF_Y3);
  unsigned short* Xhml = (unsigned short*)(ws + OFF_XH);
  unsigned short* Whml = (unsigned short*)(ws + OFF_WH);

  (void)hipMemsetAsync(ws, 0, STATS_ZERO_BYTES, stream);
  k_wcvt<<<48, 256, 0, stream>>>(Wq, Wk, Wv, Whml);
  k_main<<<512, 256, 0, stream>>>(x, Wf, bf, out, fullS, patchS);
  for (int l = 0; l < 4; ++l) {
    k_xcvt<<<256, 256, 0, stream>>>(out, Xhml, fullS, patchS, l);
    k_qkv<<<384, 256, 0, stream>>>(Whml, bq, bk, bv, Xhml, Y3, fullS, patchS, l);
    k_s<<<256, 256, 0, stream>>>(Y3, Sb, fullS, patchS, l);
    k_awr<<<512, 256, 0, stream>>>(Y3, Sb, Wr, br, out, fullS, patchS, l);
    if (l < 3) k_ftest<<<128, 256, 0, stream>>>(out, Wf, bf, patchS, fullS, l);
  }
}